// Round 10
// baseline (224.995 us; speedup 1.0000x reference)
//
#include <hip/hip_runtime.h>
#include <hip/hip_bf16.h>

// TurnGPT attention block: y = proj(softmax(causal(QK^T/8)) V), qkv = x@W_attn+b
// B=2, T=2048, C=1024, H=16, D=64. d_in/d_out are FP32; bf16 MFMA inside.
//
// LDS swizzle: glds16 can only write lane-linear images, so instead of padding
// we XOR-swizzle the 16B chunk index with ((row>>1)&3) by permuting the GLOBAL
// source column per lane. b128 readers apply the same XOR -> banks become
// (l15&1)*16 + (quad^((l15>>1)&3))*4: 8 groups x 2 lanes = 2-way (free).

typedef __bf16 bf16_t;
typedef __bf16 bf16x8 __attribute__((ext_vector_type(8)));
typedef float f32x4 __attribute__((ext_vector_type(4)));
typedef unsigned short ushort_t;

#define LOG2E 1.44269504088896340736f

__device__ __forceinline__ void glds16(const bf16_t* g, ushort_t* l) {
  __builtin_amdgcn_global_load_lds(
      (const __attribute__((address_space(1))) unsigned int*)g,
      (__attribute__((address_space(3))) unsigned int*)l, 16, 0, 0);
}

// ---------------- fused prep: cvt(x) + transpose_cvt(W_attn) + (W_proj) ------
__global__ __launch_bounds__(256) void prep_kernel(
    const float* __restrict__ x, const float* __restrict__ W_attn,
    const float* __restrict__ W_proj, ushort_t* __restrict__ Xb,
    ushort_t* __restrict__ WtA, ushort_t* __restrict__ WtP) {
  const int bid = blockIdx.x, tid = threadIdx.x;
  if (bid < 4096) {                      // cvt: x fp32 -> bf16, 4 elems/thread
    int i = bid * 256 + tid;
    float4 v = ((const float4*)x)[i];
    ushort4 o;
    o.x = __builtin_bit_cast(unsigned short, (bf16_t)v.x);
    o.y = __builtin_bit_cast(unsigned short, (bf16_t)v.y);
    o.z = __builtin_bit_cast(unsigned short, (bf16_t)v.z);
    o.w = __builtin_bit_cast(unsigned short, (bf16_t)v.w);
    ((ushort4*)Xb)[i] = o;
    return;
  }
  __shared__ ushort_t tile[32][33];
  const float* in;
  ushort_t* out;
  int R, C, bx, by;
  if (bid < 4096 + 3072) { int idx = bid - 4096; in = W_attn; out = WtA; R = 1024; C = 3072; bx = idx % 96; by = idx / 96; }
  else                   { int idx = bid - 7168; in = W_proj; out = WtP; R = 1024; C = 1024; bx = idx % 32; by = idx / 32; }
  const int tx = tid & 31, ty = tid >> 5;
  int cbase = bx * 32, rbase = by * 32;
#pragma unroll
  for (int i = ty; i < 32; i += 8)
    tile[i][tx] = __builtin_bit_cast(
        unsigned short, (bf16_t)in[(size_t)(rbase + i) * C + cbase + tx]);
  __syncthreads();
#pragma unroll
  for (int i = ty; i < 32; i += 8)
    out[(size_t)(cbase + i) * R + rbase + tx] = tile[tx][i];
}

// ---------------- batched bf16 transpose: V[bh][t][d] -> Vt[bh][d][t] --------
__global__ void transpose_v_kernel(const ushort_t* __restrict__ in,
                                   ushort_t* __restrict__ out) {
  __shared__ ushort_t tile[32][33];
  const int bh = blockIdx.z;
  const int tbase = blockIdx.x * 32, dbase = blockIdx.y * 32;
  in  += (size_t)bh * 2048 * 64;
  out += (size_t)bh * 64 * 2048;
#pragma unroll
  for (int i = threadIdx.y; i < 32; i += 8)
    tile[i][threadIdx.x] = in[(size_t)(tbase + i) * 64 + dbase + threadIdx.x];
  __syncthreads();
#pragma unroll
  for (int i = threadIdx.y; i < 32; i += 8)
    out[(size_t)(dbase + i) * 2048 + tbase + threadIdx.x] = tile[threadIdx.x][i];
}

// ---------------- shared 128x128 GEMM mainloop (dbuf + swizzled LDS) ---------
__device__ __forceinline__ void gemm128_mainloop(
    const bf16_t* __restrict__ A, const bf16_t* __restrict__ Bt, int K,
    int mtile, int ntile, ushort_t* As, ushort_t* Bs, f32x4 acc[4][4]) {
  // As/Bs: [2 buf][128 rows][32], swizzled chunks. Buf stride 4096 ushorts.
  const int tid  = threadIdx.x;
  const int lane = tid & 63, wave = tid >> 6;
  const int l15  = lane & 15, quad = lane >> 4;
  const int wrow = (wave >> 1) * 64, wcol = (wave & 1) * 64;
  const int lr = lane >> 2;                        // 16-row group
  const int lc = (((lane & 3) ^ ((lr >> 1) & 3)) * 8);  // swizzled src col
  const bf16_t* Ap = A + (size_t)(mtile + wave * 32 + lr) * K + lc;
  const bf16_t* Bp = Bt + (size_t)(ntile + wave * 32 + lr) * K + lc;
  const int rsw = (quad ^ ((l15 >> 1) & 3)) * 8;   // swizzled read chunk
  ushort_t* Asw = As + wave * 32 * 32;
  ushort_t* Bsw = Bs + wave * 32 * 32;
  const int nkb = K >> 5;
  // prologue: stage kb=0 into buf 0
#pragma unroll
  for (int c = 0; c < 2; c++) {
    glds16(Ap + (size_t)(c * 16) * K, Asw + c * 16 * 32);
    glds16(Bp + (size_t)(c * 16) * K, Bsw + c * 16 * 32);
  }
  for (int kb = 0; kb < nkb; kb++) {
    const int cur = kb & 1;
    __syncthreads();                    // drains cur-buf glds; frees 1-cur
    if (kb + 1 < nkb) {
      const int nb = (1 - cur) * 4096;
#pragma unroll
      for (int c = 0; c < 2; c++) {
        glds16(Ap + (size_t)(c * 16) * K + (kb + 1) * 32, Asw + nb + c * 16 * 32);
        glds16(Bp + (size_t)(c * 16) * K + (kb + 1) * 32, Bsw + nb + c * 16 * 32);
      }
    }
    const int cb = cur * 4096;
    bf16x8 af[4], bfr[4];
#pragma unroll
    for (int i = 0; i < 4; i++)
      af[i] = *(const bf16x8*)&As[cb + (wrow + i * 16 + l15) * 32 + rsw];
#pragma unroll
    for (int j = 0; j < 4; j++)
      bfr[j] = *(const bf16x8*)&Bs[cb + (wcol + j * 16 + l15) * 32 + rsw];
#pragma unroll
    for (int i = 0; i < 4; i++)
#pragma unroll
      for (int j = 0; j < 4; j++)
        acc[i][j] = __builtin_amdgcn_mfma_f32_16x16x32_bf16(af[i], bfr[j], acc[i][j], 0, 0, 0);
  }
}

// ---------------- QKV GEMM: Xb[4096,1024] @ W_attn + b ----------------
__global__ __launch_bounds__(256) void qkv_gemm_kernel(
    const bf16_t* __restrict__ X, const bf16_t* __restrict__ WtA,
    const float* __restrict__ bias, bf16_t* __restrict__ Qd,
    bf16_t* __restrict__ Kd, bf16_t* __restrict__ Vd) {
  __shared__ ushort_t As[2 * 128 * 32];
  __shared__ ushort_t Bs[2 * 128 * 32];
  const int mtile = blockIdx.x * 128, ntile = blockIdx.y * 128;
  f32x4 acc[4][4] = {};
  gemm128_mainloop(X, WtA, 1024, mtile, ntile, As, Bs, acc);
  const int tid = threadIdx.x, lane = tid & 63, wave = tid >> 6;
  const int l15 = lane & 15, quad = lane >> 4;
  const int wrow = (wave >> 1) * 64, wcol = (wave & 1) * 64;
#pragma unroll
  for (int j = 0; j < 4; j++) {
    int n = ntile + wcol + j * 16 + l15;           // [0,3072)
    float bv = bias[n];
    int sec = n >> 10, cc = n & 1023, h = cc >> 6, d = cc & 63;
    bf16_t* dst = (sec == 0) ? Qd : (sec == 1) ? Kd : Vd;
#pragma unroll
    for (int i = 0; i < 4; i++) {
#pragma unroll
      for (int r = 0; r < 4; r++) {
        int m = mtile + wrow + i * 16 + quad * 4 + r;   // [0,4096)
        int b = m >> 11, t = m & 2047;
        size_t bh = (size_t)(b * 16 + h);
        dst[(bh * 2048 + t) * 64 + d] = (bf16_t)(acc[i][j][r] + bv);
      }
    }
  }
}

// ---------------- flash attention (TK=64, swizzled LDS, 8 waves) -------------
// K tile: 2 kc-planes [64 t][32], V tile: 2 tHalf-planes [64 d][32]; both
// double-buffered. One barrier per 64-k-tile (2 sub-tiles of 32 inside).
__global__ __launch_bounds__(512) void attn_kernel(
    const bf16_t* __restrict__ Q, const bf16_t* __restrict__ K,
    const bf16_t* __restrict__ Vt, bf16_t* __restrict__ Y) {
  __shared__ ushort_t Ks[2][4096];       // [buf][kc*2048 + t*32 + chunk]
  __shared__ ushort_t Vs[2][4096];       // [buf][tHalf*2048 + d*32 + chunk]
  __shared__ ushort_t Ps[8][16 * 40];    // per-wave P [16 q][32 k], pad 40
  const int bh = blockIdx.y;
  const int qt = 15 - (int)blockIdx.x;   // big blocks dispatch first
  const int tid = threadIdx.x, wave = tid >> 6, lane = tid & 63;
  const int l15 = lane & 15, quad = lane >> 4;
  const bf16_t* Qh = Q + (size_t)bh * 2048 * 64;
  const bf16_t* Kh = K + (size_t)bh * 2048 * 64;
  const bf16_t* Vh = Vt + (size_t)bh * 64 * 2048;
  const int b = bh >> 4, h = bh & 15;
  const float SC = 0.125f * LOG2E;
  const int qw = qt * 128 + wave * 16;   // wave's q-row base
  const int nkt = 2 * qt + 2;            // 64-wide k-tiles

  bf16x8 qa[2];
#pragma unroll
  for (int kc = 0; kc < 2; kc++)
    qa[kc] = *(const bf16x8*)(Qh + (size_t)(qw + l15) * 64 + kc * 32 + quad * 8);

  f32x4 o[4] = {};
  float lpart[4] = {};
  const int rsw = (quad ^ ((l15 >> 1) & 3)) * 8;   // swizzled read chunk

  // staging: waves 0-3 -> K (wave w: plane kc=w>>1, t-rows (w&1)*32+[0,32)),
  //          waves 4-7 -> V (sw=w-4: plane p=sw>>1, d-rows (sw&1)*32+[0,32)).
  // 2 glds16 calls/wave (16 rows each). Source col chunk swizzled by row.
  const int lr4 = lane >> 2;
  const int csw = ((lane & 3) ^ ((lr4 >> 1) & 3)) * 8;
  const bool isK = wave < 4;
  const int sw = isK ? wave : wave - 4;
  const int rbase = (sw & 1) * 32;                 // row offset within plane
  const bf16_t* gp0;
  size_t rowstep;                                   // global stride per LDS row
  if (isK) {   // K[t][d]: row = t, col = kc*32 + swizzled chunk
    gp0 = Kh + (size_t)(rbase + lr4) * 64 + (sw >> 1) * 32 + csw;
    rowstep = 64;
  } else {     // Vt[d][t]: row = d, col = kt*64 + p*32 + swizzled chunk
    gp0 = Vh + (size_t)(rbase + lr4) * 2048 + (sw >> 1) * 32 + csw;
    rowstep = 2048;
  }
  const size_t kstep = isK ? (size_t)64 * 64 : 64;  // per-k-tile advance
  ushort_t* dst0 = (isK ? Ks[0] : Vs[0]) + (sw >> 1) * 2048 + rbase * 32;
  ushort_t* dst1 = (isK ? Ks[1] : Vs[1]) + (sw >> 1) * 2048 + rbase * 32;

#pragma unroll
  for (int c = 0; c < 2; c++)                       // prologue: tile 0 -> buf 0
    glds16(gp0 + (size_t)(c * 16) * rowstep, dst0 + c * 512);

  for (int kt = 0; kt < nkt; kt++) {
    const int cur = kt & 1;
    __syncthreads();                                // cur buf visible
    if (kt + 1 < nkt) {
      ushort_t* nd = cur ? dst0 : dst1;
#pragma unroll
      for (int c = 0; c < 2; c++)
        glds16(gp0 + (size_t)(kt + 1) * kstep + (size_t)(c * 16) * rowstep, nd + c * 512);
    }
#pragma unroll
    for (int h32 = 0; h32 < 2; h32++) {
      const int kb32 = kt * 64 + h32 * 32;          // sub-tile k base
      if (kb32 > qw + 15) break;                    // wave-uniform skip
      bf16x8 kb[2][2];
#pragma unroll
      for (int bn = 0; bn < 2; bn++)
#pragma unroll
        for (int kc = 0; kc < 2; kc++)
          kb[bn][kc] = *(const bf16x8*)&Ks[cur][kc * 2048 + (h32 * 32 + bn * 16 + l15) * 32 + rsw];
      f32x4 s[2];
      f32x4 zz = {0.f, 0.f, 0.f, 0.f};
#pragma unroll
      for (int bn = 0; bn < 2; bn++) {
        f32x4 t0 = __builtin_amdgcn_mfma_f32_16x16x32_bf16(qa[0], kb[bn][0], zz, 0, 0, 0);
        s[bn] = __builtin_amdgcn_mfma_f32_16x16x32_bf16(qa[1], kb[bn][1], t0, 0, 0, 0);
      }
      const bool diagish = (kb32 + 31 > qw);
#pragma unroll
      for (int r = 0; r < 4; r++) {
        int row = qw + quad * 4 + r;
        float v0 = s[0][r] * SC;
        float v1 = s[1][r] * SC;
        if (diagish) {
          int c0 = kb32 + l15;
          if (c0 > row) v0 = -1e5f;
          if (c0 + 16 > row) v1 = -1e5f;
        }
        float p0 = exp2f(fminf(v0, 115.0f));
        float p1 = exp2f(fminf(v1, 115.0f));
        lpart[r] += p0 + p1;
        int prow = (quad * 4 + r) * 40;
        Ps[wave][prow + l15]      = __builtin_bit_cast(unsigned short, (bf16_t)p0);
        Ps[wave][prow + 16 + l15] = __builtin_bit_cast(unsigned short, (bf16_t)p1);
      }
      __asm__ volatile("s_waitcnt lgkmcnt(0)" ::: "memory");
      bf16x8 pa, vb[4];
      pa = *(const bf16x8*)&Ps[wave][l15 * 40 + quad * 8];
#pragma unroll
      for (int ns = 0; ns < 4; ns++)
        vb[ns] = *(const bf16x8*)&Vs[cur][h32 * 2048 + (ns * 16 + l15) * 32 + rsw];
#pragma unroll
      for (int ns = 0; ns < 4; ns++)
        o[ns] = __builtin_amdgcn_mfma_f32_16x16x32_bf16(pa, vb[ns], o[ns], 0, 0, 0);
    }
  }
  // epilogue: reduce l across the 16-lane row group, then y = o / l
#pragma unroll
  for (int r = 0; r < 4; r++) {
    float l = lpart[r];
#pragma unroll
    for (int off = 1; off < 16; off <<= 1) l += __shfl_xor(l, off);
    float inv_l = 1.0f / fmaxf(l, 1e-30f);
    int t = qw + quad * 4 + r;
#pragma unroll
    for (int ns = 0; ns < 4; ns++) {
      int c = h * 64 + ns * 16 + l15;
      Y[((size_t)(b * 2048 + t)) * 1024 + c] = (bf16_t)(o[ns][r] * inv_l);
    }
  }
}

// ---------------- proj GEMM: Yb[4096,1024] @ W_proj + b -> FP32 out ----------
__global__ __launch_bounds__(256) void proj_gemm_kernel(
    const bf16_t* __restrict__ Yb, const bf16_t* __restrict__ WtP,
    const float* __restrict__ bias, float* __restrict__ out) {
  __shared__ ushort_t As[2 * 128 * 32];
  __shared__ ushort_t Bs[2 * 128 * 32];
  const int mtile = blockIdx.x * 128, ntile = blockIdx.y * 128;
  f32x4 acc[4][4] = {};
  gemm128_mainloop(Yb, WtP, 1024, mtile, ntile, As, Bs, acc);
  const int tid = threadIdx.x, lane = tid & 63, wave = tid >> 6;
  const int l15 = lane & 15, quad = lane >> 4;
  const int wrow = (wave >> 1) * 64, wcol = (wave & 1) * 64;
#pragma unroll
  for (int j = 0; j < 4; j++) {
    int n = ntile + wcol + j * 16 + l15;
    float bv = bias[n];
#pragma unroll
    for (int i = 0; i < 4; i++) {
#pragma unroll
      for (int r = 0; r < 4; r++) {
        int m = mtile + wrow + i * 16 + quad * 4 + r;
        out[(size_t)m * 1024 + n] = acc[i][j][r] + bv;
      }
    }
  }
}

extern "C" void kernel_launch(void* const* d_in, const int* in_sizes, int n_in,
                              void* d_out, int out_size, void* d_ws, size_t ws_size,
                              hipStream_t stream) {
  const float* x      = (const float*)d_in[0];   // [2,2048,1024]
  const float* W_attn = (const float*)d_in[1];   // [1024,3072]
  const float* b_attn = (const float*)d_in[2];   // [3072]
  const float* W_proj = (const float*)d_in[3];   // [1024,1024]
  const float* b_proj = (const float*)d_in[4];   // [1024]
  float* out = (float*)d_out;                    // [2,2048,1024]

  bf16_t* ws  = (bf16_t*)d_ws;
  bf16_t* WtA = ws;                                // 3072*1024
  bf16_t* WtP = WtA + (size_t)3072 * 1024;         // 1024*1024
  bf16_t* Xb  = WtP + (size_t)1024 * 1024;         // 4096*1024
  bf16_t* Qb  = Xb + (size_t)4194304;
  bf16_t* Kb  = Qb + (size_t)4194304;
  bf16_t* Vb  = Kb + (size_t)4194304;
  bf16_t* Vtb = Vb + (size_t)4194304;
  bf16_t* Yb  = Vtb + (size_t)4194304;             // ~56 MB bf16 total

  prep_kernel<<<8192, 256, 0, stream>>>(x, W_attn, W_proj,
      (ushort_t*)Xb, (ushort_t*)WtA, (ushort_t*)WtP);
  qkv_gemm_kernel<<<dim3(32, 24), 256, 0, stream>>>(Xb, WtA, b_attn, Qb, Kb, Vb);
  transpose_v_kernel<<<dim3(64, 2, 32), dim3(32, 8), 0, stream>>>(
      (const ushort_t*)Vb, (ushort_t*)Vtb);
  attn_kernel<<<dim3(16, 32), 512, 0, stream>>>(Qb, Kb, Vtb, Yb);
  proj_gemm_kernel<<<dim3(32, 8), 256, 0, stream>>>(Yb, WtP, b_proj, out);
}

// Round 11
// 213.195 us; speedup vs baseline: 1.0553x; 1.0553x over previous
//
#include <hip/hip_runtime.h>
#include <hip/hip_bf16.h>

// TurnGPT attention block: y = proj(softmax(causal(QK^T/8)) V), qkv = x@W_attn+b
// B=2, T=2048, C=1024, H=16, D=64. d_in/d_out are FP32; bf16 MFMA inside.
//
// LDS swizzle: glds16 can only write lane-linear images, so instead of padding
// we XOR-swizzle the 16B chunk index with ((row%16)>>1)&3 by permuting the
// GLOBAL source column per lane. Readers apply the same XOR -> 2-way banks.

typedef __bf16 bf16_t;
typedef __bf16 bf16x8 __attribute__((ext_vector_type(8)));
typedef float f32x4 __attribute__((ext_vector_type(4)));
typedef unsigned short ushort_t;

#define LOG2E 1.44269504088896340736f

__device__ __forceinline__ void glds16(const bf16_t* g, ushort_t* l) {
  __builtin_amdgcn_global_load_lds(
      (const __attribute__((address_space(1))) unsigned int*)g,
      (__attribute__((address_space(3))) unsigned int*)l, 16, 0, 0);
}

// ---------------- fused prep: cvt(x) + transpose_cvt(W_attn) + (W_proj) ------
__global__ __launch_bounds__(256) void prep_kernel(
    const float* __restrict__ x, const float* __restrict__ W_attn,
    const float* __restrict__ W_proj, ushort_t* __restrict__ Xb,
    ushort_t* __restrict__ WtA, ushort_t* __restrict__ WtP) {
  const int bid = blockIdx.x, tid = threadIdx.x;
  if (bid < 4096) {                      // cvt: x fp32 -> bf16, 4 elems/thread
    int i = bid * 256 + tid;
    float4 v = ((const float4*)x)[i];
    ushort4 o;
    o.x = __builtin_bit_cast(unsigned short, (bf16_t)v.x);
    o.y = __builtin_bit_cast(unsigned short, (bf16_t)v.y);
    o.z = __builtin_bit_cast(unsigned short, (bf16_t)v.z);
    o.w = __builtin_bit_cast(unsigned short, (bf16_t)v.w);
    ((ushort4*)Xb)[i] = o;
    return;
  }
  __shared__ ushort_t tile[32][33];
  const float* in;
  ushort_t* out;
  int C, bx, by;
  if (bid < 4096 + 3072) { int idx = bid - 4096; in = W_attn; out = WtA; C = 3072; bx = idx % 96; by = idx / 96; }
  else                   { int idx = bid - 7168; in = W_proj; out = WtP; C = 1024; bx = idx % 32; by = idx / 32; }
  const int tx = tid & 31, ty = tid >> 5;
  int cbase = bx * 32, rbase = by * 32;
#pragma unroll
  for (int i = ty; i < 32; i += 8)
    tile[i][tx] = __builtin_bit_cast(
        unsigned short, (bf16_t)in[(size_t)(rbase + i) * C + cbase + tx]);
  __syncthreads();
#pragma unroll
  for (int i = ty; i < 32; i += 8)
    out[(size_t)(cbase + i) * 1024 + rbase + tx] = tile[tx][i];
}

// ---------------- shared 128x128 GEMM mainloop (single-buf + swizzled LDS) ---
__device__ __forceinline__ void gemm128_mainloop(
    const bf16_t* __restrict__ A, const bf16_t* __restrict__ Bt, int K,
    int mtile, int ntile, ushort_t* As, ushort_t* Bs, f32x4 acc[4][4]) {
  const int tid  = threadIdx.x;
  const int lane = tid & 63, wave = tid >> 6;
  const int l15  = lane & 15, quad = lane >> 4;
  const int wrow = (wave >> 1) * 64, wcol = (wave & 1) * 64;
  const int lr = lane >> 2;                        // row within 16-row group
  const int lc = (((lane & 3) ^ ((lr >> 1) & 3)) * 8);  // swizzled src col
  const bf16_t* Ap = A + (size_t)(mtile + wave * 32 + lr) * K + lc;
  const bf16_t* Bp = Bt + (size_t)(ntile + wave * 32 + lr) * K + lc;
  const int rsw = (quad ^ ((l15 >> 1) & 3)) * 8;   // swizzled read chunk
  ushort_t* Asw = As + wave * 32 * 32;
  ushort_t* Bsw = Bs + wave * 32 * 32;
  for (int kb = 0; kb < K; kb += 32) {
    __syncthreads();                    // prior iter's LDS reads done
#pragma unroll
    for (int c = 0; c < 2; c++) {       // 16 rows per call (64 lanes x 16B)
      glds16(Ap + (size_t)(c * 16) * K + kb, Asw + c * 16 * 32);
      glds16(Bp + (size_t)(c * 16) * K + kb, Bsw + c * 16 * 32);
    }
    __syncthreads();                    // drains vmcnt -> staged data visible
    bf16x8 af[4], bfr[4];
#pragma unroll
    for (int i = 0; i < 4; i++)
      af[i] = *(const bf16x8*)&As[(wrow + i * 16 + l15) * 32 + rsw];
#pragma unroll
    for (int j = 0; j < 4; j++)
      bfr[j] = *(const bf16x8*)&Bs[(wcol + j * 16 + l15) * 32 + rsw];
#pragma unroll
    for (int i = 0; i < 4; i++)
#pragma unroll
      for (int j = 0; j < 4; j++)
        acc[i][j] = __builtin_amdgcn_mfma_f32_16x16x32_bf16(af[i], bfr[j], acc[i][j], 0, 0, 0);
  }
}

// ---------------- QKV GEMM: Xb[4096,1024] @ W_attn + b ----------------
// epilogue: Q,K -> [B*H][T][D] coalesced; V -> Vt[B*H][D][T] direct scatter
// (2B stores, L2 write-combined; measured faster than a separate transpose).
__global__ __launch_bounds__(256) void qkv_gemm_kernel(
    const bf16_t* __restrict__ X, const bf16_t* __restrict__ WtA,
    const float* __restrict__ bias, bf16_t* __restrict__ Qd,
    bf16_t* __restrict__ Kd, bf16_t* __restrict__ Vtd) {
  __shared__ ushort_t As[128 * 32];
  __shared__ ushort_t Bs[128 * 32];
  const int mtile = blockIdx.x * 128, ntile = blockIdx.y * 128;
  f32x4 acc[4][4] = {};
  gemm128_mainloop(X, WtA, 1024, mtile, ntile, As, Bs, acc);
  const int tid = threadIdx.x, lane = tid & 63, wave = tid >> 6;
  const int l15 = lane & 15, quad = lane >> 4;
  const int wrow = (wave >> 1) * 64, wcol = (wave & 1) * 64;
#pragma unroll
  for (int j = 0; j < 4; j++) {
    int n = ntile + wcol + j * 16 + l15;           // [0,3072)
    float bv = bias[n];
    int sec = n >> 10, cc = n & 1023, h = cc >> 6, d = cc & 63;
#pragma unroll
    for (int i = 0; i < 4; i++) {
#pragma unroll
      for (int r = 0; r < 4; r++) {
        int m = mtile + wrow + i * 16 + quad * 4 + r;   // [0,4096)
        int b = m >> 11, t = m & 2047;
        size_t bh = (size_t)(b * 16 + h);
        bf16_t v = (bf16_t)(acc[i][j][r] + bv);
        if (sec == 0)      Qd[(bh * 2048 + t) * 64 + d] = v;
        else if (sec == 1) Kd[(bh * 2048 + t) * 64 + d] = v;
        else               Vtd[(bh * 64 + d) * 2048 + t] = v;
      }
    }
  }
}

// ---------------- flash attention (TK=64, dual-subtile ILP) ------------------
// 8 waves x 16 q-rows. Per 64-k-tile: both 32-wide sub-tiles processed as two
// INDEPENDENT chains (QKa+QKb -> softmax a+b -> one fence -> PVa+PVb) so the
// scheduler can hide each chain's latency behind the other. Dual P buffers.
__global__ __launch_bounds__(512) void attn_kernel(
    const bf16_t* __restrict__ Q, const bf16_t* __restrict__ K,
    const bf16_t* __restrict__ Vt, bf16_t* __restrict__ Y) {
  __shared__ ushort_t Ks[2][4096];       // [buf][kc*2048 + t*32 + chunk]
  __shared__ ushort_t Vs[2][4096];       // [buf][tHalf*2048 + d*32 + chunk]
  __shared__ ushort_t Ps[8][2][16 * 40]; // per-wave, per-subtile P [16 q][32 k]
  const int bh = blockIdx.y;
  const int qt = 15 - (int)blockIdx.x;   // big blocks dispatch first
  const int tid = threadIdx.x, wave = tid >> 6, lane = tid & 63;
  const int l15 = lane & 15, quad = lane >> 4;
  const bf16_t* Qh = Q + (size_t)bh * 2048 * 64;
  const bf16_t* Kh = K + (size_t)bh * 2048 * 64;
  const bf16_t* Vh = Vt + (size_t)bh * 64 * 2048;
  const int b = bh >> 4, h = bh & 15;
  const float SC = 0.125f * LOG2E;
  const int qw = qt * 128 + wave * 16;   // wave's q-row base
  const int nkt = 2 * qt + 2;            // 64-wide k-tiles

  bf16x8 qa[2];
#pragma unroll
  for (int kc = 0; kc < 2; kc++)
    qa[kc] = *(const bf16x8*)(Qh + (size_t)(qw + l15) * 64 + kc * 32 + quad * 8);

  f32x4 o[4] = {};
  float lpart[4] = {};
  const int rsw = (quad ^ ((l15 >> 1) & 3)) * 8;   // swizzled read chunk

  // staging: waves 0-3 -> K, waves 4-7 -> V; 2 glds16/wave/tile, swizzled cols
  const int lr4 = lane >> 2;
  const int csw = ((lane & 3) ^ ((lr4 >> 1) & 3)) * 8;
  const bool isK = wave < 4;
  const int sw = isK ? wave : wave - 4;
  const int rbase = (sw & 1) * 32;
  const bf16_t* gp0;
  size_t rowstep;
  if (isK) { gp0 = Kh + (size_t)(rbase + lr4) * 64 + (sw >> 1) * 32 + csw;  rowstep = 64; }
  else     { gp0 = Vh + (size_t)(rbase + lr4) * 2048 + (sw >> 1) * 32 + csw; rowstep = 2048; }
  const size_t kstep = isK ? (size_t)64 * 64 : 64;
  ushort_t* dst0 = (isK ? Ks[0] : Vs[0]) + (sw >> 1) * 2048 + rbase * 32;
  ushort_t* dst1 = (isK ? Ks[1] : Vs[1]) + (sw >> 1) * 2048 + rbase * 32;

#pragma unroll
  for (int c = 0; c < 2; c++)                       // prologue: tile 0 -> buf 0
    glds16(gp0 + (size_t)(c * 16) * rowstep, dst0 + c * 512);

  f32x4 zz = {0.f, 0.f, 0.f, 0.f};
  for (int kt = 0; kt < nkt; kt++) {
    const int cur = kt & 1;
    __syncthreads();                                // cur buf visible
    if (kt + 1 < nkt) {
      ushort_t* nd = cur ? dst0 : dst1;
#pragma unroll
      for (int c = 0; c < 2; c++)
        glds16(gp0 + (size_t)(kt + 1) * kstep + (size_t)(c * 16) * rowstep, nd + c * 512);
    }
    const int kb0 = kt * 64, kb1 = kt * 64 + 32;
    const bool a0 = (kb0 <= qw + 15), a1 = (kb1 <= qw + 15);  // wave-uniform
    if (a1) {
      // ---- both sub-tiles: two independent chains ----
      bf16x8 kbA[2][2], kbB[2][2];
#pragma unroll
      for (int bn = 0; bn < 2; bn++)
#pragma unroll
        for (int kc = 0; kc < 2; kc++) {
          kbA[bn][kc] = *(const bf16x8*)&Ks[cur][kc * 2048 + (bn * 16 + l15) * 32 + rsw];
          kbB[bn][kc] = *(const bf16x8*)&Ks[cur][kc * 2048 + (32 + bn * 16 + l15) * 32 + rsw];
        }
      f32x4 sA[2], sB[2];
#pragma unroll
      for (int bn = 0; bn < 2; bn++) {
        f32x4 tA = __builtin_amdgcn_mfma_f32_16x16x32_bf16(qa[0], kbA[bn][0], zz, 0, 0, 0);
        sA[bn] = __builtin_amdgcn_mfma_f32_16x16x32_bf16(qa[1], kbA[bn][1], tA, 0, 0, 0);
        f32x4 tB = __builtin_amdgcn_mfma_f32_16x16x32_bf16(qa[0], kbB[bn][0], zz, 0, 0, 0);
        sB[bn] = __builtin_amdgcn_mfma_f32_16x16x32_bf16(qa[1], kbB[bn][1], tB, 0, 0, 0);
      }
      const bool dgA = (kb0 + 31 > qw), dgB = (kb1 + 31 > qw);
#pragma unroll
      for (int r = 0; r < 4; r++) {
        int row = qw + quad * 4 + r;
        float a_v0 = sA[0][r] * SC, a_v1 = sA[1][r] * SC;
        float b_v0 = sB[0][r] * SC, b_v1 = sB[1][r] * SC;
        if (dgA) {
          int c0 = kb0 + l15;
          if (c0 > row) a_v0 = -1e5f;
          if (c0 + 16 > row) a_v1 = -1e5f;
        }
        if (dgB) {
          int c0 = kb1 + l15;
          if (c0 > row) b_v0 = -1e5f;
          if (c0 + 16 > row) b_v1 = -1e5f;
        }
        float pa0 = exp2f(fminf(a_v0, 115.0f)), pa1 = exp2f(fminf(a_v1, 115.0f));
        float pb0 = exp2f(fminf(b_v0, 115.0f)), pb1 = exp2f(fminf(b_v1, 115.0f));
        lpart[r] += (pa0 + pa1) + (pb0 + pb1);
        int prow = (quad * 4 + r) * 40;
        Ps[wave][0][prow + l15]      = __builtin_bit_cast(unsigned short, (bf16_t)pa0);
        Ps[wave][0][prow + 16 + l15] = __builtin_bit_cast(unsigned short, (bf16_t)pa1);
        Ps[wave][1][prow + l15]      = __builtin_bit_cast(unsigned short, (bf16_t)pb0);
        Ps[wave][1][prow + 16 + l15] = __builtin_bit_cast(unsigned short, (bf16_t)pb1);
      }
      __asm__ volatile("s_waitcnt lgkmcnt(0)" ::: "memory");
      bf16x8 paA, paB, vbA[4], vbB[4];
      paA = *(const bf16x8*)&Ps[wave][0][l15 * 40 + quad * 8];
      paB = *(const bf16x8*)&Ps[wave][1][l15 * 40 + quad * 8];
#pragma unroll
      for (int ns = 0; ns < 4; ns++) {
        vbA[ns] = *(const bf16x8*)&Vs[cur][(ns * 16 + l15) * 32 + rsw];
        vbB[ns] = *(const bf16x8*)&Vs[cur][2048 + (ns * 16 + l15) * 32 + rsw];
      }
#pragma unroll
      for (int ns = 0; ns < 4; ns++)
        o[ns] = __builtin_amdgcn_mfma_f32_16x16x32_bf16(paA, vbA[ns], o[ns], 0, 0, 0);
#pragma unroll
      for (int ns = 0; ns < 4; ns++)
        o[ns] = __builtin_amdgcn_mfma_f32_16x16x32_bf16(paB, vbB[ns], o[ns], 0, 0, 0);
    } else if (a0) {
      // ---- only sub-tile 0 (diagonal edge) ----
      bf16x8 kb[2][2];
#pragma unroll
      for (int bn = 0; bn < 2; bn++)
#pragma unroll
        for (int kc = 0; kc < 2; kc++)
          kb[bn][kc] = *(const bf16x8*)&Ks[cur][kc * 2048 + (bn * 16 + l15) * 32 + rsw];
      f32x4 s[2];
#pragma unroll
      for (int bn = 0; bn < 2; bn++) {
        f32x4 t0 = __builtin_amdgcn_mfma_f32_16x16x32_bf16(qa[0], kb[bn][0], zz, 0, 0, 0);
        s[bn] = __builtin_amdgcn_mfma_f32_16x16x32_bf16(qa[1], kb[bn][1], t0, 0, 0, 0);
      }
      const bool dg = (kb0 + 31 > qw);
#pragma unroll
      for (int r = 0; r < 4; r++) {
        int row = qw + quad * 4 + r;
        float v0 = s[0][r] * SC, v1 = s[1][r] * SC;
        if (dg) {
          int c0 = kb0 + l15;
          if (c0 > row) v0 = -1e5f;
          if (c0 + 16 > row) v1 = -1e5f;
        }
        float p0 = exp2f(fminf(v0, 115.0f)), p1 = exp2f(fminf(v1, 115.0f));
        lpart[r] += p0 + p1;
        int prow = (quad * 4 + r) * 40;
        Ps[wave][0][prow + l15]      = __builtin_bit_cast(unsigned short, (bf16_t)p0);
        Ps[wave][0][prow + 16 + l15] = __builtin_bit_cast(unsigned short, (bf16_t)p1);
      }
      __asm__ volatile("s_waitcnt lgkmcnt(0)" ::: "memory");
      bf16x8 pa, vb[4];
      pa = *(const bf16x8*)&Ps[wave][0][l15 * 40 + quad * 8];
#pragma unroll
      for (int ns = 0; ns < 4; ns++)
        vb[ns] = *(const bf16x8*)&Vs[cur][(ns * 16 + l15) * 32 + rsw];
#pragma unroll
      for (int ns = 0; ns < 4; ns++)
        o[ns] = __builtin_amdgcn_mfma_f32_16x16x32_bf16(pa, vb[ns], o[ns], 0, 0, 0);
    }
  }
  // epilogue: reduce l across the 16-lane row group, then y = o / l
#pragma unroll
  for (int r = 0; r < 4; r++) {
    float l = lpart[r];
#pragma unroll
    for (int off = 1; off < 16; off <<= 1) l += __shfl_xor(l, off);
    float inv_l = 1.0f / fmaxf(l, 1e-30f);
    int t = qw + quad * 4 + r;
#pragma unroll
    for (int ns = 0; ns < 4; ns++) {
      int c = h * 64 + ns * 16 + l15;
      Y[((size_t)(b * 2048 + t)) * 1024 + c] = (bf16_t)(o[ns][r] * inv_l);
    }
  }
}

// ---------------- proj GEMM: Yb[4096,1024] @ W_proj + b -> FP32 out ----------
__global__ __launch_bounds__(256) void proj_gemm_kernel(
    const bf16_t* __restrict__ Yb, const bf16_t* __restrict__ WtP,
    const float* __restrict__ bias, float* __restrict__ out) {
  __shared__ ushort_t As[128 * 32];
  __shared__ ushort_t Bs[128 * 32];
  const int mtile = blockIdx.x * 128, ntile = blockIdx.y * 128;
  f32x4 acc[4][4] = {};
  gemm128_mainloop(Yb, WtP, 1024, mtile, ntile, As, Bs, acc);
  const int tid = threadIdx.x, lane = tid & 63, wave = tid >> 6;
  const int l15 = lane & 15, quad = lane >> 4;
  const int wrow = (wave >> 1) * 64, wcol = (wave & 1) * 64;
#pragma unroll
  for (int j = 0; j < 4; j++) {
    int n = ntile + wcol + j * 16 + l15;
    float bv = bias[n];
#pragma unroll
    for (int i = 0; i < 4; i++) {
#pragma unroll
      for (int r = 0; r < 4; r++) {
        int m = mtile + wrow + i * 16 + quad * 4 + r;
        out[(size_t)m * 1024 + n] = acc[i][j][r] + bv;
      }
    }
  }
}

extern "C" void kernel_launch(void* const* d_in, const int* in_sizes, int n_in,
                              void* d_out, int out_size, void* d_ws, size_t ws_size,
                              hipStream_t stream) {
  const float* x      = (const float*)d_in[0];   // [2,2048,1024]
  const float* W_attn = (const float*)d_in[1];   // [1024,3072]
  const float* b_attn = (const float*)d_in[2];   // [3072]
  const float* W_proj = (const float*)d_in[3];   // [1024,1024]
  const float* b_proj = (const float*)d_in[4];   // [1024]
  float* out = (float*)d_out;                    // [2,2048,1024]

  bf16_t* ws  = (bf16_t*)d_ws;
  bf16_t* WtA = ws;                                // 3072*1024
  bf16_t* WtP = WtA + (size_t)3072 * 1024;         // 1024*1024
  bf16_t* Xb  = WtP + (size_t)1024 * 1024;         // 4096*1024
  bf16_t* Qb  = Xb + (size_t)4194304;
  bf16_t* Kb  = Qb + (size_t)4194304;
  bf16_t* Vtb = Kb + (size_t)4194304;
  bf16_t* Yb  = Vtb + (size_t)4194304;             // ~48 MB bf16 total

  prep_kernel<<<8192, 256, 0, stream>>>(x, W_attn, W_proj,
      (ushort_t*)Xb, (ushort_t*)WtA, (ushort_t*)WtP);
  qkv_gemm_kernel<<<dim3(32, 24), 256, 0, stream>>>(Xb, WtA, b_attn, Qb, Kb, Vtb);
  attn_kernel<<<dim3(16, 32), 512, 0, stream>>>(Qb, Kb, Vtb, Yb);
  proj_gemm_kernel<<<dim3(32, 8), 256, 0, stream>>>(Yb, WtP, b_proj, out);
}